// Round 26
// baseline (202.665 us; speedup 1.0000x reference)
//
#include <hip/hip_runtime.h>
#include <hip/hip_bf16.h>
#include <math.h>

#define BATCH 8
#define CFULL 256
#define HEADS 8
#define CH 32
#define NTOK 16384
#define TN 64
#define TTN 32
#define TK 16
#define KSLD 40
#define KSL 24
#define EPS 1e-6f

// xs tile swizzle: channel-index XOR spreads banks (units of 8 shorts = 16B).
#define SWZ(tok) ((((tok) & 7) << 3) ^ ((((tok) >> 3) & 3) << 6))

typedef __bf16 bf16x8 __attribute__((ext_vector_type(8)));
typedef float f32x4 __attribute__((ext_vector_type(4)));
typedef float f32x16 __attribute__((ext_vector_type(16)));
typedef float fvec4 __attribute__((ext_vector_type(4)));
typedef unsigned short ushort8v __attribute__((ext_vector_type(8)));
typedef int int4v __attribute__((ext_vector_type(4)));

__device__ __forceinline__ unsigned short bf16bits(float f) {
    return __builtin_bit_cast(unsigned short, (__bf16)f);
}
__device__ __forceinline__ float softplus_f(float x) {
    return fmaxf(x, 0.0f) + __logf(1.0f + __expf(-fabsf(x)));
}

// 4x4 transpose within a quad of lanes.
__device__ __forceinline__ void quad_transpose(fvec4& a, int lane) {
    const bool o1 = lane & 1, o2 = lane & 2;
    float s1 = o1 ? a.x : a.y; float g1 = __shfl_xor(s1, 1);
    float s2 = o1 ? a.z : a.w; float g2 = __shfl_xor(s2, 1);
    a.x = o1 ? g1 : a.x;  a.y = o1 ? a.y : g1;
    a.z = o1 ? g2 : a.z;  a.w = o1 ? a.w : g2;
    float s3 = o2 ? a.x : a.z; float g3 = __shfl_xor(s3, 2);
    float s4 = o2 ? a.y : a.w; float g4 = __shfl_xor(s4, 2);
    a.x = o2 ? g3 : a.x;  a.z = o2 ? a.z : g3;
    a.y = o2 ? g4 : a.y;  a.w = o2 ? a.w : g4;
}

// Stage one 64-token x tile into xs (tok-major bf16, SWZ swizzled) from f32 x.
template <int NW>
__device__ __forceinline__ void stage_x(const float* __restrict__ xb, int n0,
                                        unsigned short* xs, int wv, int lane) {
    const int q4 = lane & 3;
    const int t0 = (lane >> 2) << 2;
    constexpr int G = 64 / NW;   // channel-groups of 4 per wave
    #pragma unroll
    for (int g = 0; g < G; ++g) {
        const int c0 = wv * (G * 4) + g * 4;
        fvec4 a = __builtin_nontemporal_load(
            (const fvec4*)(xb + (size_t)(c0 + q4) * NTOK + n0 + t0));
        quad_transpose(a, lane);
        ushort4 pk;
        pk.x = bf16bits(a.x); pk.y = bf16bits(a.y);
        pk.z = bf16bits(a.z); pk.w = bf16bits(a.w);
        *(ushort4*)&xs[lane * CFULL + (c0 ^ SWZ(lane))] = pk;
    }
}

// Stage one 32-token tile (8 waves, 4 tok rows per wave, 2 DMA per lane).
__device__ __forceinline__ void stage32(const unsigned short* __restrict__ xTb,
                                        int n0, unsigned short* buf, int wv, int lane) {
    const unsigned short* src = xTb + (size_t)(n0 + wv * 4) * CFULL + lane * 8;
    unsigned short* dst = buf + wv * 4 * CFULL;   // wave-uniform
    #pragma unroll
    for (int i = 0; i < 2; ++i) {
        __builtin_amdgcn_global_load_lds(
            (const __attribute__((address_space(1))) unsigned int*)(src + i * 512),
            (__attribute__((address_space(3))) unsigned int*)(dst + i * 512),
            16, 0, 0);
    }
}

// Stage one 16-token tile (8 waves, 2 tok rows per wave, 1 DMA per lane).
__device__ __forceinline__ void stage16(const unsigned short* __restrict__ xTb,
                                        int n0, unsigned short* buf, int wv, int lane) {
    const unsigned short* src = xTb + (size_t)(n0 + wv * 2) * CFULL + lane * 8;
    unsigned short* dst = buf + wv * 2 * CFULL;   // wave-uniform
    __builtin_amdgcn_global_load_lds(
        (const __attribute__((address_space(1))) unsigned int*)src,
        (__attribute__((address_space(3))) unsigned int*)dst,
        16, 0, 0);
}

// Convert the three weight matrices to bf16 once per launch.
__global__ void prep_w(const float* __restrict__ Wq, const float* __restrict__ Wk,
                       const float* __restrict__ Wv, unsigned short* __restrict__ dst)
{
    const int i = blockIdx.x * 256 + threadIdx.x;
    const float* src = (i < 65536) ? Wq : ((i < 131072) ? Wk : Wv);
    dst[i] = bf16bits(src[i & 65535]);
}

// ---------------------------------------------------------------------------
// Transpose kernel: x[b][ch][tok] f32 -> xT[b][tok][ch] bf16, pre-swizzled.
// ---------------------------------------------------------------------------
__global__ __launch_bounds__(512)
void xpose(const float* __restrict__ x, unsigned short* __restrict__ xT)
{
    __shared__ __align__(16) unsigned short xs[TN * CFULL];
    const int tid = threadIdx.x;
    const int lane = tid & 63;
    const int wv = tid >> 6;          // 0..7
    const int b = blockIdx.x >> 8;
    const int n0 = (blockIdx.x & 255) * TN;

    stage_x<8>(x + (size_t)b * CFULL * NTOK, n0, xs, wv, lane);
    __syncthreads();
    int4v* dst = (int4v*)(xT + ((size_t)b * NTOK + n0) * CFULL);
    const int4v* src = (const int4v*)xs;
    #pragma unroll
    for (int i = 0; i < 4; ++i)
        dst[i * 512 + tid] = src[i * 512 + tid];
}

// ---------------------------------------------------------------------------
// Kernel 1: 512 threads / 8 waves; wave wv owns head wv (och [wv*32, wv*32+32)).
// 16-token tiles, double-buffered xs. LDS 40 KB -> 4 blocks/CU (32 waves/CU,
// the wave cap) vs 2 blocks at TTN=32: occupancy play for the latency-bound
// kernel. Per-tile swizzle base sb corrects the 64-token-baked xT swizzle for
// odd-16 tile offsets. ks/vs pad-24 (48B rows, 16B aligned), wave-local.
// ---------------------------------------------------------------------------
__global__ __launch_bounds__(512)
void k1_kv(const unsigned short* __restrict__ xT,
           const unsigned short* __restrict__ Wk,
           const unsigned short* __restrict__ Wv,
           const float* __restrict__ bk, const float* __restrict__ bv,
           float* __restrict__ kvpart, float* __restrict__ kspart,
           int bpb, int ntiles)
{
    __shared__ __align__(16) unsigned short xs0[TK * CFULL];    // 8 KB
    __shared__ __align__(16) unsigned short xs1[TK * CFULL];    // 8 KB
    __shared__ __align__(16) unsigned short ks[CFULL * KSL];    // 12 KB
    __shared__ __align__(16) unsigned short vs[CFULL * KSL];    // 12 KB

    const int tid = threadIdx.x;
    const int lane = tid & 63;
    const int wv = tid >> 6;          // 0..7; wave wv == head wv
    const int l15 = lane & 15;
    const int lhi = lane >> 4;
    const int bid = blockIdx.x;
    const int b = bid / bpb;
    const int blk = bid % bpb;
    const int tokbase = blk * (ntiles * TK);
    const unsigned short* xTb = xT + (size_t)b * NTOK * CFULL;

    float bkr[2], bvr[2];
    #pragma unroll
    for (int of = 0; of < 2; ++of) {
        bkr[of] = bk[wv * 32 + of * 16 + l15];
        bvr[of] = bv[wv * 32 + of * 16 + l15];
    }

    f32x16 kvacc = {};
    float ksum[2] = {0.f, 0.f};

    stage16(xTb, tokbase, xs0, wv, lane);
    __syncthreads();                  // prologue tile resident

    for (int t = 0; t < ntiles; ++t) {
        unsigned short* cur = (t & 1) ? xs1 : xs0;
        unsigned short* nxt = (t & 1) ? xs0 : xs1;
        if (t + 1 < ntiles)
            stage16(xTb, tokbase + (t + 1) * TK, nxt, wv, lane);  // async, in flight
        const int n0 = tokbase + t * TK;
        const int sb = ((n0 >> 3) & 2) << 6;   // swizzle base for odd-16 offsets

        // ---- K projection (D[tok16][och32]) + softplus -> ks (wave-local rows)
        {
            f32x4 acc[2] = {};
            #pragma unroll
            for (int kk = 0; kk < 8; ++kk) {
                const int ch0 = kk * 32 + lhi * 8;
                bf16x8 af = *(const bf16x8*)&cur[l15 * CFULL + ((ch0 ^ SWZ(l15)) ^ sb)];
                #pragma unroll
                for (int of = 0; of < 2; ++of) {
                    const int och = wv * 32 + of * 16 + l15;
                    bf16x8 bfr = *(const bf16x8*)&Wk[och * CFULL + ch0];
                    acc[of] = __builtin_amdgcn_mfma_f32_16x16x32_bf16(af, bfr, acc[of], 0, 0, 0);
                }
            }
            #pragma unroll
            for (int of = 0; of < 2; ++of) {
                const int och = wv * 32 + of * 16 + l15;
                const float bias = bkr[of];
                float v0 = softplus_f(acc[of][0] + bias);
                float v1 = softplus_f(acc[of][1] + bias);
                float v2 = softplus_f(acc[of][2] + bias);
                float v3 = softplus_f(acc[of][3] + bias);
                ksum[of] += v0 + v1 + v2 + v3;
                ushort4 pk;
                pk.x = bf16bits(v0); pk.y = bf16bits(v1);
                pk.z = bf16bits(v2); pk.w = bf16bits(v3);
                *(ushort4*)&ks[och * KSL + lhi * 4] = pk;
            }
        }

        // ---- V projection -> vs (wave-local rows, separate buffer, no barrier)
        {
            f32x4 acc[2] = {};
            #pragma unroll
            for (int kk = 0; kk < 8; ++kk) {
                const int ch0 = kk * 32 + lhi * 8;
                bf16x8 af = *(const bf16x8*)&cur[l15 * CFULL + ((ch0 ^ SWZ(l15)) ^ sb)];
                #pragma unroll
                for (int of = 0; of < 2; ++of) {
                    const int och = wv * 32 + of * 16 + l15;
                    bf16x8 bfr = *(const bf16x8*)&Wv[och * CFULL + ch0];
                    acc[of] = __builtin_amdgcn_mfma_f32_16x16x32_bf16(af, bfr, acc[of], 0, 0, 0);
                }
            }
            #pragma unroll
            for (int of = 0; of < 2; ++of) {
                const int och = wv * 32 + of * 16 + l15;
                const float bias = bvr[of];
                ushort4 pk;
                pk.x = bf16bits(acc[of][0] + bias);
                pk.y = bf16bits(acc[of][1] + bias);
                pk.z = bf16bits(acc[of][2] + bias);
                pk.w = bf16bits(acc[of][3] + bias);
                *(ushort4*)&vs[och * KSL + lhi * 4] = pk;
            }
        }

        // ---- kv accumulation (head wv; ks/vs rows wave-local), K-dim = 16 toks
        {
            const int l31 = lane & 31;
            const int hi = lane >> 5;
            const int row = wv * 32 + l31;
            bf16x8 ak = *(const bf16x8*)&ks[row * KSL + hi * 8];
            bf16x8 av = *(const bf16x8*)&vs[row * KSL + hi * 8];
            kvacc = __builtin_amdgcn_mfma_f32_32x32x16_bf16(ak, av, kvacc, 0, 0, 0);
        }

        __syncthreads();   // drains next-tile stage + all waves done reading cur
    }

    // ---- epilogue: coalesced partial stores (no atomics)
    #pragma unroll
    for (int of = 0; of < 2; ++of) {
        float v = ksum[of];
        v += __shfl_xor(v, 16);
        v += __shfl_xor(v, 32);
        if (lhi == 0) kspart[bid * CFULL + wv * 32 + of * 16 + l15] = v;
    }
    {
        float* kvp = kvpart + ((size_t)bid << 13);
        const int l31 = lane & 31;
        const int hi = lane >> 5;
        #pragma unroll
        for (int q = 0; q < 4; ++q) {
            const int m0 = 8 * q + 4 * hi;
            f32x4 s;
            s[0] = kvacc[4 * q + 0]; s[1] = kvacc[4 * q + 1];
            s[2] = kvacc[4 * q + 2]; s[3] = kvacc[4 * q + 3];
            *(f32x4*)&kvp[wv * 1024 + l31 * 32 + m0] = s;  // [p=wv][c][m]
        }
    }
}

// ---------------------------------------------------------------------------
// Reduce partials: kvT[b][p][c][m] (bf16), kse[b][ch] = ksum + EPS (f32)
// ---------------------------------------------------------------------------
__global__ __launch_bounds__(256)
void k1r(const float* __restrict__ kvpart, const float* __restrict__ kspart,
         unsigned short* __restrict__ kvT, float* __restrict__ kse, int bpb)
{
    const int o = blockIdx.x * 256 + threadIdx.x;   // 0..65535
    const int b = o >> 13;
    const int r = o & 8191;
    float s = 0.f;
    for (int j = 0; j < bpb; ++j)
        s += kvpart[((size_t)(b * bpb + j) << 13) + r];
    kvT[o] = bf16bits(s);
    if (blockIdx.x < BATCH) {
        const int bb = blockIdx.x;
        float t = 0.f;
        for (int j = 0; j < bpb; ++j)
            t += kspart[(bb * bpb + j) * CFULL + threadIdx.x];
        kse[bb * CFULL + threadIdx.x] = t + EPS;
    }
}

// ---------------------------------------------------------------------------
// Kernel 2: 512 threads / 8 waves; wave wv owns head wv. k1-style pipeline:
// 32-token tiles, double-buffered staging, q in separate qs buffer (wave-local
// epilogue -> f32 denominator via shfl -> PV). One barrier per tile.
// (n0 is a multiple of 32 here so the 64-token-baked swizzle needs no sb.)
// ---------------------------------------------------------------------------
__global__ __launch_bounds__(512)
void k2_out(const unsigned short* __restrict__ xT,
            const unsigned short* __restrict__ Wq,
            const float* __restrict__ bq,
            const unsigned short* __restrict__ kvT, const float* __restrict__ ksef,
            float* __restrict__ outp, int bpb, int ntiles)
{
    __shared__ __align__(16) unsigned short xs0[TTN * CFULL];   // 16 KB
    __shared__ __align__(16) unsigned short xs1[TTN * CFULL];   // 16 KB
    __shared__ __align__(16) unsigned short qs[TTN * CFULL];    // 16 KB
    __shared__ float normls[HEADS][TTN];

    const int tid = threadIdx.x;
    const int lane = tid & 63;
    const int wv = tid >> 6;          // 0..7; wave wv == head wv
    const int l15 = lane & 15;
    const int lhi = lane >> 4;
    const int bid = blockIdx.x;
    const int b = bid / bpb;
    const int blk = bid % bpb;
    const int tokbase = blk * (ntiles * TTN);
    const unsigned short* xTb = xT + (size_t)b * NTOK * CFULL;
    float* ob = outp + (size_t)b * CFULL * NTOK;

    stage32(xTb, tokbase, xs0, wv, lane);

    // per-block constants (amortized over ntiles): kv fragments, bias, kse
    bf16x8 bh[2];
    {
        const int base = (b * HEADS + wv) << 10;
        #pragma unroll
        for (int hf = 0; hf < 2; ++hf)
            bh[hf] = *(const bf16x8*)&kvT[base + (hf * 16 + l15) * 32 + lhi * 8];
    }
    float bq0[2][4], ksq[2][4];
    #pragma unroll
    for (int of = 0; of < 2; ++of) {
        const int och0 = wv * 32 + of * 16 + lhi * 4;
        #pragma unroll
        for (int r = 0; r < 4; ++r) {
            bq0[of][r] = bq[och0 + r];
            ksq[of][r] = ksef[b * CFULL + och0 + r];
        }
    }

    __syncthreads();                  // prologue tile resident

    for (int t = 0; t < ntiles; ++t) {
        unsigned short* cur = (t & 1) ? xs1 : xs0;
        unsigned short* nxt = (t & 1) ? xs0 : xs1;
        if (t + 1 < ntiles)
            stage32(xTb, tokbase + (t + 1) * TTN, nxt, wv, lane);  // async, in flight
        const int n0 = tokbase + t * TTN;

        // ---- Q projection (D[och32][tok32])
        f32x4 acc[2][2] = {};
        #pragma unroll
        for (int kk = 0; kk < 8; ++kk) {
            const int ch0 = kk * 32 + lhi * 8;
            bf16x8 aw[2], bx[2];
            #pragma unroll
            for (int of = 0; of < 2; ++of)
                aw[of] = *(const bf16x8*)&Wq[(wv * 32 + of * 16 + l15) * CFULL + ch0];
            #pragma unroll
            for (int nf = 0; nf < 2; ++nf) {
                const int tok = nf * 16 + l15;
                bx[nf] = *(const bf16x8*)&cur[tok * CFULL + (ch0 ^ SWZ(tok))];
            }
            #pragma unroll
            for (int of = 0; of < 2; ++of)
                #pragma unroll
                for (int nf = 0; nf < 2; ++nf)
                    acc[of][nf] = __builtin_amdgcn_mfma_f32_16x16x32_bf16(aw[of], bx[nf], acc[of][nf], 0, 0, 0);
        }

        // ---- epilogue: softplus + f32 denominator partials + pack to qs
        float dpart[2] = {0.f, 0.f};
        #pragma unroll
        for (int of = 0; of < 2; ++of) {
            #pragma unroll
            for (int nf = 0; nf < 2; ++nf) {
                float q0 = softplus_f(acc[of][nf][0] + bq0[of][0]);
                float q1 = softplus_f(acc[of][nf][1] + bq0[of][1]);
                float q2 = softplus_f(acc[of][nf][2] + bq0[of][2]);
                float q3 = softplus_f(acc[of][nf][3] + bq0[of][3]);
                dpart[nf] += q0 * ksq[of][0] + q1 * ksq[of][1] +
                             q2 * ksq[of][2] + q3 * ksq[of][3];
                ushort4 pk;
                pk.x = bf16bits(q0); pk.y = bf16bits(q1);
                pk.z = bf16bits(q2); pk.w = bf16bits(q3);
                const int tok = nf * 16 + l15;
                const int och0 = wv * 32 + of * 16 + lhi * 4;
                *(ushort4*)&qs[tok * CFULL + (och0 ^ SWZ(tok))] = pk;
            }
        }
        #pragma unroll
        for (int nf = 0; nf < 2; ++nf) {
            float d = dpart[nf];
            d += __shfl_xor(d, 16);
            d += __shfl_xor(d, 32);
            if (lhi == 0) normls[wv][nf * 16 + l15] = 1.0f / d;
        }
        // no barrier: qs rows + normls for head wv are wave-local

        // ---- PV: D[tok][c] = sum_m q[m][tok] kv[m][c]; scale; plain stores
        #pragma unroll
        for (int nf = 0; nf < 2; ++nf) {
            const int tok = nf * 16 + l15;
            bf16x8 af = *(const bf16x8*)&qs[tok * CFULL + ((wv * 32 + lhi * 8) ^ SWZ(tok))];
            f32x4 oA = {}, oB = {};
            oA = __builtin_amdgcn_mfma_f32_16x16x32_bf16(af, bh[0], oA, 0, 0, 0);
            oB = __builtin_amdgcn_mfma_f32_16x16x32_bf16(af, bh[1], oB, 0, 0, 0);
            const int tb = nf * 16 + lhi * 4;
            const f32x4 nrm = *(const f32x4*)&normls[wv][tb];
            f32x4 sA, sB;
            sA[0] = oA[0] * nrm[0]; sA[1] = oA[1] * nrm[1];
            sA[2] = oA[2] * nrm[2]; sA[3] = oA[3] * nrm[3];
            sB[0] = oB[0] * nrm[0]; sB[1] = oB[1] * nrm[1];
            sB[2] = oB[2] * nrm[2]; sB[3] = oB[3] * nrm[3];
            *(f32x4*)&ob[(size_t)(wv * 32 + l15) * NTOK + n0 + tb] = sA;
            *(f32x4*)&ob[(size_t)(wv * 32 + 16 + l15) * NTOK + n0 + tb] = sB;
        }

        __syncthreads();   // drains next-tile stage + all waves done reading cur
    }
}

extern "C" void kernel_launch(void* const* d_in, const int* in_sizes, int n_in,
                              void* d_out, int out_size, void* d_ws, size_t ws_size,
                              hipStream_t stream)
{
    const float* x  = (const float*)d_in[0];
    const float* Wq = (const float*)d_in[1];
    const float* bq = (const float*)d_in[2];
    const float* Wk = (const float*)d_in[3];
    const float* bk = (const float*)d_in[4];
    const float* Wv = (const float*)d_in[5];
    const float* bv = (const float*)d_in[6];
    float* out = (float*)d_out;

    unsigned char* ws = (unsigned char*)d_ws;
    unsigned short* wbf = (unsigned short*)ws;                    // 384 KB
    unsigned short* kvT = (unsigned short*)(ws + 393216);         // 128 KB
    float* kse = (float*)(ws + 524288);                           // 8 KB

    const size_t xT_sz = (size_t)BATCH * NTOK * CFULL * 2;        // 64 MB

    int bpb = 64;
    size_t ksp_off = 532480;
    size_t kvp_off = ksp_off + (size_t)BATCH * bpb * CFULL * 4;
    size_t kvp_sz  = (size_t)BATCH * bpb * 8192 * 4;
    if (ws_size < kvp_off + kvp_sz + xT_sz) {
        bpb = 16;
        kvp_off = ksp_off + (size_t)BATCH * bpb * CFULL * 4;
        kvp_sz  = (size_t)BATCH * bpb * 8192 * 4;
    }
    float* kspart = (float*)(ws + ksp_off);
    float* kvpart = (float*)(ws + kvp_off);
    unsigned short* xT = (unsigned short*)(ws + kvp_off + kvp_sz);
    const int ntiles = NTOK / TK / bpb;         // 16-token tiles in k1

    const int bpb2 = 128;                       // k2: 1024 blocks x 4 tiles
    const int ntiles2 = NTOK / TTN / bpb2;

    hipLaunchKernelGGL(prep_w, dim3(768), dim3(256), 0, stream, Wq, Wk, Wv, wbf);
    hipLaunchKernelGGL(xpose, dim3(BATCH * 256), dim3(512), 0, stream, x, xT);
    hipLaunchKernelGGL(k1_kv, dim3(BATCH * bpb), dim3(512), 0, stream,
                       xT, wbf + 65536, wbf + 2 * 65536, bk, bv,
                       kvpart, kspart, bpb, ntiles);
    hipLaunchKernelGGL(k1r, dim3(256), dim3(256), 0, stream,
                       kvpart, kspart, kvT, kse, bpb);
    hipLaunchKernelGGL(k2_out, dim3(BATCH * bpb2), dim3(512), 0, stream,
                       xT, wbf, bq, kvT, kse, out, bpb2, ntiles2);
}

// Round 27
// 198.962 us; speedup vs baseline: 1.0186x; 1.0186x over previous
//
#include <hip/hip_runtime.h>
#include <hip/hip_bf16.h>
#include <math.h>

#define BATCH 8
#define CFULL 256
#define HEADS 8
#define CH 32
#define NTOK 16384
#define TN 64
#define TTN 32
#define KSLD 40
#define EPS 1e-6f

// xs tile swizzle: channel-index XOR spreads banks (units of 8 shorts = 16B).
#define SWZ(tok) ((((tok) & 7) << 3) ^ ((((tok) >> 3) & 3) << 6))

typedef __bf16 bf16x8 __attribute__((ext_vector_type(8)));
typedef float f32x4 __attribute__((ext_vector_type(4)));
typedef float f32x16 __attribute__((ext_vector_type(16)));
typedef float fvec4 __attribute__((ext_vector_type(4)));
typedef unsigned short ushort8v __attribute__((ext_vector_type(8)));
typedef int int4v __attribute__((ext_vector_type(4)));

__device__ __forceinline__ unsigned short bf16bits(float f) {
    return __builtin_bit_cast(unsigned short, (__bf16)f);
}
__device__ __forceinline__ float softplus_f(float x) {
    return fmaxf(x, 0.0f) + __logf(1.0f + __expf(-fabsf(x)));
}

// 4x4 transpose within a quad of lanes.
__device__ __forceinline__ void quad_transpose(fvec4& a, int lane) {
    const bool o1 = lane & 1, o2 = lane & 2;
    float s1 = o1 ? a.x : a.y; float g1 = __shfl_xor(s1, 1);
    float s2 = o1 ? a.z : a.w; float g2 = __shfl_xor(s2, 1);
    a.x = o1 ? g1 : a.x;  a.y = o1 ? a.y : g1;
    a.z = o1 ? g2 : a.z;  a.w = o1 ? a.w : g2;
    float s3 = o2 ? a.x : a.z; float g3 = __shfl_xor(s3, 2);
    float s4 = o2 ? a.y : a.w; float g4 = __shfl_xor(s4, 2);
    a.x = o2 ? g3 : a.x;  a.z = o2 ? a.z : g3;
    a.y = o2 ? g4 : a.y;  a.w = o2 ? a.w : g4;
}

// Stage one 64-token x tile into xs (tok-major bf16, SWZ swizzled) from f32 x.
template <int NW>
__device__ __forceinline__ void stage_x(const float* __restrict__ xb, int n0,
                                        unsigned short* xs, int wv, int lane) {
    const int q4 = lane & 3;
    const int t0 = (lane >> 2) << 2;
    constexpr int G = 64 / NW;   // channel-groups of 4 per wave
    #pragma unroll
    for (int g = 0; g < G; ++g) {
        const int c0 = wv * (G * 4) + g * 4;
        fvec4 a = __builtin_nontemporal_load(
            (const fvec4*)(xb + (size_t)(c0 + q4) * NTOK + n0 + t0));
        quad_transpose(a, lane);
        ushort4 pk;
        pk.x = bf16bits(a.x); pk.y = bf16bits(a.y);
        pk.z = bf16bits(a.z); pk.w = bf16bits(a.w);
        *(ushort4*)&xs[lane * CFULL + (c0 ^ SWZ(lane))] = pk;
    }
}

// Stage one 32-token tile (8 waves, 4 tok rows per wave, 2 DMA per lane).
__device__ __forceinline__ void stage32(const unsigned short* __restrict__ xTb,
                                        int n0, unsigned short* buf, int wv, int lane) {
    const unsigned short* src = xTb + (size_t)(n0 + wv * 4) * CFULL + lane * 8;
    unsigned short* dst = buf + wv * 4 * CFULL;   // wave-uniform
    #pragma unroll
    for (int i = 0; i < 2; ++i) {
        __builtin_amdgcn_global_load_lds(
            (const __attribute__((address_space(1))) unsigned int*)(src + i * 512),
            (__attribute__((address_space(3))) unsigned int*)(dst + i * 512),
            16, 0, 0);
    }
}

// Convert the three weight matrices to bf16 once per launch.
__global__ void prep_w(const float* __restrict__ Wq, const float* __restrict__ Wk,
                       const float* __restrict__ Wv, unsigned short* __restrict__ dst)
{
    const int i = blockIdx.x * 256 + threadIdx.x;
    const float* src = (i < 65536) ? Wq : ((i < 131072) ? Wk : Wv);
    dst[i] = bf16bits(src[i & 65535]);
}

// ---------------------------------------------------------------------------
// Transpose kernel: x[b][ch][tok] f32 -> xT[b][tok][ch] bf16, pre-swizzled.
// ---------------------------------------------------------------------------
__global__ __launch_bounds__(512)
void xpose(const float* __restrict__ x, unsigned short* __restrict__ xT)
{
    __shared__ __align__(16) unsigned short xs[TN * CFULL];
    const int tid = threadIdx.x;
    const int lane = tid & 63;
    const int wv = tid >> 6;          // 0..7
    const int b = blockIdx.x >> 8;
    const int n0 = (blockIdx.x & 255) * TN;

    stage_x<8>(x + (size_t)b * CFULL * NTOK, n0, xs, wv, lane);
    __syncthreads();
    int4v* dst = (int4v*)(xT + ((size_t)b * NTOK + n0) * CFULL);
    const int4v* src = (const int4v*)xs;
    #pragma unroll
    for (int i = 0; i < 4; ++i)
        dst[i * 512 + tid] = src[i * 512 + tid];
}

// ---------------------------------------------------------------------------
// Kernel 1: 512 threads / 8 waves; wave wv owns head wv (och [wv*32, wv*32+32)).
// 32-token tiles, DOUBLE-BUFFERED xs: stage(t+1) issued before compute(t),
// drained by the single end-of-tile barrier. ks/vs stride-40 padded, wave-local.
// ---------------------------------------------------------------------------
__global__ __launch_bounds__(512)
void k1_kv(const unsigned short* __restrict__ xT,
           const unsigned short* __restrict__ Wk,
           const unsigned short* __restrict__ Wv,
           const float* __restrict__ bk, const float* __restrict__ bv,
           float* __restrict__ kvpart, float* __restrict__ kspart,
           int bpb, int ntiles)
{
    __shared__ __align__(16) unsigned short xs0[TTN * CFULL];   // 16 KB
    __shared__ __align__(16) unsigned short xs1[TTN * CFULL];   // 16 KB
    __shared__ __align__(16) unsigned short ks[CFULL * KSLD];   // 20 KB (pad 40)
    __shared__ __align__(16) unsigned short vs[CFULL * KSLD];   // 20 KB

    const int tid = threadIdx.x;
    const int lane = tid & 63;
    const int wv = tid >> 6;          // 0..7; wave wv == head wv
    const int l15 = lane & 15;
    const int lhi = lane >> 4;
    const int bid = blockIdx.x;
    const int b = bid / bpb;
    const int blk = bid % bpb;
    const int tokbase = blk * (ntiles * TTN);
    const unsigned short* xTb = xT + (size_t)b * NTOK * CFULL;

    float bkr[2], bvr[2];
    #pragma unroll
    for (int of = 0; of < 2; ++of) {
        bkr[of] = bk[wv * 32 + of * 16 + l15];
        bvr[of] = bv[wv * 32 + of * 16 + l15];
    }

    f32x16 kvacc = {};
    float ksum[2] = {0.f, 0.f};

    stage32(xTb, tokbase, xs0, wv, lane);
    __syncthreads();                  // prologue tile resident

    for (int t = 0; t < ntiles; ++t) {
        unsigned short* cur = (t & 1) ? xs1 : xs0;
        unsigned short* nxt = (t & 1) ? xs0 : xs1;
        if (t + 1 < ntiles)
            stage32(xTb, tokbase + (t + 1) * TTN, nxt, wv, lane);  // async, in flight

        // ---- K projection (D[tok32][och32]) + softplus -> ks (wave-local rows)
        {
            f32x4 acc[2][2] = {};
            #pragma unroll
            for (int kk = 0; kk < 8; ++kk) {
                const int ch0 = kk * 32 + lhi * 8;
                bf16x8 af[2], bfr[2];
                #pragma unroll
                for (int tf = 0; tf < 2; ++tf) {
                    const int tok = tf * 16 + l15;
                    af[tf] = *(const bf16x8*)&cur[tok * CFULL + (ch0 ^ SWZ(tok))];
                }
                #pragma unroll
                for (int of = 0; of < 2; ++of) {
                    const int och = wv * 32 + of * 16 + l15;
                    bfr[of] = *(const bf16x8*)&Wk[och * CFULL + ch0];
                }
                #pragma unroll
                for (int tf = 0; tf < 2; ++tf)
                    #pragma unroll
                    for (int of = 0; of < 2; ++of)
                        acc[tf][of] = __builtin_amdgcn_mfma_f32_16x16x32_bf16(af[tf], bfr[of], acc[tf][of], 0, 0, 0);
            }
            #pragma unroll
            for (int tf = 0; tf < 2; ++tf) {
                #pragma unroll
                for (int of = 0; of < 2; ++of) {
                    const int och = wv * 32 + of * 16 + l15;
                    const float bias = bkr[of];
                    float v0 = softplus_f(acc[tf][of][0] + bias);
                    float v1 = softplus_f(acc[tf][of][1] + bias);
                    float v2 = softplus_f(acc[tf][of][2] + bias);
                    float v3 = softplus_f(acc[tf][of][3] + bias);
                    ksum[of] += v0 + v1 + v2 + v3;
                    ushort4 pk;
                    pk.x = bf16bits(v0); pk.y = bf16bits(v1);
                    pk.z = bf16bits(v2); pk.w = bf16bits(v3);
                    *(ushort4*)&ks[och * KSLD + tf * 16 + lhi * 4] = pk;
                }
            }
        }

        // ---- V projection -> vs (wave-local rows, separate buffer, no barrier)
        {
            f32x4 acc[2][2] = {};
            #pragma unroll
            for (int kk = 0; kk < 8; ++kk) {
                const int ch0 = kk * 32 + lhi * 8;
                bf16x8 af[2], bfr[2];
                #pragma unroll
                for (int tf = 0; tf < 2; ++tf) {
                    const int tok = tf * 16 + l15;
                    af[tf] = *(const bf16x8*)&cur[tok * CFULL + (ch0 ^ SWZ(tok))];
                }
                #pragma unroll
                for (int of = 0; of < 2; ++of) {
                    const int och = wv * 32 + of * 16 + l15;
                    bfr[of] = *(const bf16x8*)&Wv[och * CFULL + ch0];
                }
                #pragma unroll
                for (int tf = 0; tf < 2; ++tf)
                    #pragma unroll
                    for (int of = 0; of < 2; ++of)
                        acc[tf][of] = __builtin_amdgcn_mfma_f32_16x16x32_bf16(af[tf], bfr[of], acc[tf][of], 0, 0, 0);
            }
            #pragma unroll
            for (int tf = 0; tf < 2; ++tf) {
                #pragma unroll
                for (int of = 0; of < 2; ++of) {
                    const int och = wv * 32 + of * 16 + l15;
                    const float bias = bvr[of];
                    ushort4 pk;
                    pk.x = bf16bits(acc[tf][of][0] + bias);
                    pk.y = bf16bits(acc[tf][of][1] + bias);
                    pk.z = bf16bits(acc[tf][of][2] + bias);
                    pk.w = bf16bits(acc[tf][of][3] + bias);
                    *(ushort4*)&vs[och * KSLD + tf * 16 + lhi * 4] = pk;
                }
            }
        }

        // ---- kv accumulation (head wv; ks/vs rows wave-local)
        {
            const int l31 = lane & 31;
            const int hi = lane >> 5;
            const int row = wv * 32 + l31;
            #pragma unroll
            for (int ts = 0; ts < 2; ++ts) {
                const int sw = ts * 16 + hi * 8;
                bf16x8 ak = *(const bf16x8*)&ks[row * KSLD + sw];
                bf16x8 av = *(const bf16x8*)&vs[row * KSLD + sw];
                kvacc = __builtin_amdgcn_mfma_f32_32x32x16_bf16(ak, av, kvacc, 0, 0, 0);
            }
        }

        __syncthreads();   // drains next-tile stage + all waves done reading cur
    }

    // ---- epilogue: coalesced partial stores (no atomics)
    #pragma unroll
    for (int of = 0; of < 2; ++of) {
        float v = ksum[of];
        v += __shfl_xor(v, 16);
        v += __shfl_xor(v, 32);
        if (lhi == 0) kspart[bid * CFULL + wv * 32 + of * 16 + l15] = v;
    }
    {
        float* kvp = kvpart + ((size_t)bid << 13);
        const int l31 = lane & 31;
        const int hi = lane >> 5;
        #pragma unroll
        for (int q = 0; q < 4; ++q) {
            const int m0 = 8 * q + 4 * hi;
            f32x4 s;
            s[0] = kvacc[4 * q + 0]; s[1] = kvacc[4 * q + 1];
            s[2] = kvacc[4 * q + 2]; s[3] = kvacc[4 * q + 3];
            *(f32x4*)&kvp[wv * 1024 + l31 * 32 + m0] = s;  // [p=wv][c][m]
        }
    }
}

// ---------------------------------------------------------------------------
// Reduce partials: kvT[b][p][c][m] (bf16), kse[b][ch] = ksum + EPS (f32)
// ---------------------------------------------------------------------------
__global__ __launch_bounds__(256)
void k1r(const float* __restrict__ kvpart, const float* __restrict__ kspart,
         unsigned short* __restrict__ kvT, float* __restrict__ kse, int bpb)
{
    const int o = blockIdx.x * 256 + threadIdx.x;   // 0..65535
    const int b = o >> 13;
    const int r = o & 8191;
    float s = 0.f;
    for (int j = 0; j < bpb; ++j)
        s += kvpart[((size_t)(b * bpb + j) << 13) + r];
    kvT[o] = bf16bits(s);
    if (blockIdx.x < BATCH) {
        const int bb = blockIdx.x;
        float t = 0.f;
        for (int j = 0; j < bpb; ++j)
            t += kspart[(bb * bpb + j) * CFULL + threadIdx.x];
        kse[bb * CFULL + threadIdx.x] = t + EPS;
    }
}

// ---------------------------------------------------------------------------
// Kernel 2: 512 threads / 8 waves; wave wv owns head wv. k1-style pipeline:
// 32-token tiles, double-buffered staging, q in separate qs buffer (wave-local
// epilogue -> f32 denominator via shfl -> PV). One barrier per tile.
// ---------------------------------------------------------------------------
__global__ __launch_bounds__(512)
void k2_out(const unsigned short* __restrict__ xT,
            const unsigned short* __restrict__ Wq,
            const float* __restrict__ bq,
            const unsigned short* __restrict__ kvT, const float* __restrict__ ksef,
            float* __restrict__ outp, int bpb, int ntiles)
{
    __shared__ __align__(16) unsigned short xs0[TTN * CFULL];   // 16 KB
    __shared__ __align__(16) unsigned short xs1[TTN * CFULL];   // 16 KB
    __shared__ __align__(16) unsigned short qs[TTN * CFULL];    // 16 KB
    __shared__ float normls[HEADS][TTN];

    const int tid = threadIdx.x;
    const int lane = tid & 63;
    const int wv = tid >> 6;          // 0..7; wave wv == head wv
    const int l15 = lane & 15;
    const int lhi = lane >> 4;
    const int bid = blockIdx.x;
    const int b = bid / bpb;
    const int blk = bid % bpb;
    const int tokbase = blk * (ntiles * TTN);
    const unsigned short* xTb = xT + (size_t)b * NTOK * CFULL;
    float* ob = outp + (size_t)b * CFULL * NTOK;

    stage32(xTb, tokbase, xs0, wv, lane);

    // per-block constants (amortized over ntiles): kv fragments, bias, kse
    bf16x8 bh[2];
    {
        const int base = (b * HEADS + wv) << 10;
        #pragma unroll
        for (int hf = 0; hf < 2; ++hf)
            bh[hf] = *(const bf16x8*)&kvT[base + (hf * 16 + l15) * 32 + lhi * 8];
    }
    float bq0[2][4], ksq[2][4];
    #pragma unroll
    for (int of = 0; of < 2; ++of) {
        const int och0 = wv * 32 + of * 16 + lhi * 4;
        #pragma unroll
        for (int r = 0; r < 4; ++r) {
            bq0[of][r] = bq[och0 + r];
            ksq[of][r] = ksef[b * CFULL + och0 + r];
        }
    }

    __syncthreads();                  // prologue tile resident

    for (int t = 0; t < ntiles; ++t) {
        unsigned short* cur = (t & 1) ? xs1 : xs0;
        unsigned short* nxt = (t & 1) ? xs0 : xs1;
        if (t + 1 < ntiles)
            stage32(xTb, tokbase + (t + 1) * TTN, nxt, wv, lane);  // async, in flight
        const int n0 = tokbase + t * TTN;

        // ---- Q projection (D[och32][tok32])
        f32x4 acc[2][2] = {};
        #pragma unroll
        for (int kk = 0; kk < 8; ++kk) {
            const int ch0 = kk * 32 + lhi * 8;
            bf16x8 aw[2], bx[2];
            #pragma unroll
            for (int of = 0; of < 2; ++of)
                aw[of] = *(const bf16x8*)&Wq[(wv * 32 + of * 16 + l15) * CFULL + ch0];
            #pragma unroll
            for (int nf = 0; nf < 2; ++nf) {
                const int tok = nf * 16 + l15;
                bx[nf] = *(const bf16x8*)&cur[tok * CFULL + (ch0 ^ SWZ(tok))];
            }
            #pragma unroll
            for (int of = 0; of < 2; ++of)
                #pragma unroll
                for (int nf = 0; nf < 2; ++nf)
                    acc[of][nf] = __builtin_amdgcn_mfma_f32_16x16x32_bf16(aw[of], bx[nf], acc[of][nf], 0, 0, 0);
        }

        // ---- epilogue: softplus + f32 denominator partials + pack to qs
        float dpart[2] = {0.f, 0.f};
        #pragma unroll
        for (int of = 0; of < 2; ++of) {
            #pragma unroll
            for (int nf = 0; nf < 2; ++nf) {
                float q0 = softplus_f(acc[of][nf][0] + bq0[of][0]);
                float q1 = softplus_f(acc[of][nf][1] + bq0[of][1]);
                float q2 = softplus_f(acc[of][nf][2] + bq0[of][2]);
                float q3 = softplus_f(acc[of][nf][3] + bq0[of][3]);
                dpart[nf] += q0 * ksq[of][0] + q1 * ksq[of][1] +
                             q2 * ksq[of][2] + q3 * ksq[of][3];
                ushort4 pk;
                pk.x = bf16bits(q0); pk.y = bf16bits(q1);
                pk.z = bf16bits(q2); pk.w = bf16bits(q3);
                const int tok = nf * 16 + l15;
                const int och0 = wv * 32 + of * 16 + lhi * 4;
                *(ushort4*)&qs[tok * CFULL + (och0 ^ SWZ(tok))] = pk;
            }
        }
        #pragma unroll
        for (int nf = 0; nf < 2; ++nf) {
            float d = dpart[nf];
            d += __shfl_xor(d, 16);
            d += __shfl_xor(d, 32);
            if (lhi == 0) normls[wv][nf * 16 + l15] = 1.0f / d;
        }
        // no barrier: qs rows + normls for head wv are wave-local

        // ---- PV: D[tok][c] = sum_m q[m][tok] kv[m][c]; scale; plain stores
        #pragma unroll
        for (int nf = 0; nf < 2; ++nf) {
            const int tok = nf * 16 + l15;
            bf16x8 af = *(const bf16x8*)&qs[tok * CFULL + ((wv * 32 + lhi * 8) ^ SWZ(tok))];
            f32x4 oA = {}, oB = {};
            oA = __builtin_amdgcn_mfma_f32_16x16x32_bf16(af, bh[0], oA, 0, 0, 0);
            oB = __builtin_amdgcn_mfma_f32_16x16x32_bf16(af, bh[1], oB, 0, 0, 0);
            const int tb = nf * 16 + lhi * 4;
            const f32x4 nrm = *(const f32x4*)&normls[wv][tb];
            f32x4 sA, sB;
            sA[0] = oA[0] * nrm[0]; sA[1] = oA[1] * nrm[1];
            sA[2] = oA[2] * nrm[2]; sA[3] = oA[3] * nrm[3];
            sB[0] = oB[0] * nrm[0]; sB[1] = oB[1] * nrm[1];
            sB[2] = oB[2] * nrm[2]; sB[3] = oB[3] * nrm[3];
            *(f32x4*)&ob[(size_t)(wv * 32 + l15) * NTOK + n0 + tb] = sA;
            *(f32x4*)&ob[(size_t)(wv * 32 + 16 + l15) * NTOK + n0 + tb] = sB;
        }

        __syncthreads();   // drains next-tile stage + all waves done reading cur
    }
}

extern "C" void kernel_launch(void* const* d_in, const int* in_sizes, int n_in,
                              void* d_out, int out_size, void* d_ws, size_t ws_size,
                              hipStream_t stream)
{
    const float* x  = (const float*)d_in[0];
    const float* Wq = (const float*)d_in[1];
    const float* bq = (const float*)d_in[2];
    const float* Wk = (const float*)d_in[3];
    const float* bk = (const float*)d_in[4];
    const float* Wv = (const float*)d_in[5];
    const float* bv = (const float*)d_in[6];
    float* out = (float*)d_out;

    unsigned char* ws = (unsigned char*)d_ws;
    unsigned short* wbf = (unsigned short*)ws;                    // 384 KB
    unsigned short* kvT = (unsigned short*)(ws + 393216);         // 128 KB
    float* kse = (float*)(ws + 524288);                           // 8 KB

    const size_t xT_sz = (size_t)BATCH * NTOK * CFULL * 2;        // 64 MB

    int bpb = 64;
    size_t ksp_off = 532480;
    size_t kvp_off = ksp_off + (size_t)BATCH * bpb * CFULL * 4;
    size_t kvp_sz  = (size_t)BATCH * bpb * 8192 * 4;
    if (ws_size < kvp_off + kvp_sz + xT_sz) {
        bpb = 16;
        kvp_off = ksp_off + (size_t)BATCH * bpb * CFULL * 4;
        kvp_sz  = (size_t)BATCH * bpb * 8192 * 4;
    }
    float* kspart = (float*)(ws + ksp_off);
    float* kvpart = (float*)(ws + kvp_off);
    unsigned short* xT = (unsigned short*)(ws + kvp_off + kvp_sz);
    const int ntiles = NTOK / TTN / bpb;

    const int bpb2 = 128;                       // k2: 1024 blocks x 4 tiles
    const int ntiles2 = NTOK / TTN / bpb2;

    hipLaunchKernelGGL(prep_w, dim3(768), dim3(256), 0, stream, Wq, Wk, Wv, wbf);
    hipLaunchKernelGGL(xpose, dim3(BATCH * 256), dim3(512), 0, stream, x, xT);
    hipLaunchKernelGGL(k1_kv, dim3(BATCH * bpb), dim3(512), 0, stream,
                       xT, wbf + 65536, wbf + 2 * 65536, bk, bv,
                       kvpart, kspart, bpb, ntiles);
    hipLaunchKernelGGL(k1r, dim3(256), dim3(256), 0, stream,
                       kvpart, kspart, kvT, kse, bpb);
    hipLaunchKernelGGL(k2_out, dim3(BATCH * bpb2), dim3(512), 0, stream,
                       xT, wbf, bq, kvT, kse, out, bpb2, ntiles2);
}